// Round 13
// baseline (630.726 us; speedup 1.0000x reference)
//
#include <hip/hip_runtime.h>
#include <math.h>

#define TT 512
#define BB 512
#define CC 32
#define CIN 33
#define HH 128
#define EPSF 1e-12f
#define CH 16              // timesteps per x-chunk staged in LDS
#define NCH (TT / CH)

typedef _Float16 half8 __attribute__((ext_vector_type(8)));
typedef _Float16 half4v __attribute__((ext_vector_type(4)));
typedef _Float16 half2v __attribute__((ext_vector_type(2)));
typedef float f32x4 __attribute__((ext_vector_type(4)));

#define MFMA16H(a, b, c) __builtin_amdgcn_mfma_f32_16x16x32_f16(a, b, c, 0, 0, 0)

__device__ __forceinline__ float fsig(float x) {
    return __builtin_amdgcn_rcpf(1.f + __expf(-x));
}
__device__ __forceinline__ float ftanh(float x) {
    return 1.f - 2.f * __builtin_amdgcn_rcpf(1.f + __expf(2.f * x));
}
// full-wave (64) sum via DPP; result valid on lane 63 ONLY.
__device__ __forceinline__ float wave_sum_dpp(float x) {
    x += __int_as_float(__builtin_amdgcn_update_dpp(0, __float_as_int(x), 0x111, 0xf, 0xf, true));
    x += __int_as_float(__builtin_amdgcn_update_dpp(0, __float_as_int(x), 0x112, 0xf, 0xf, true));
    x += __int_as_float(__builtin_amdgcn_update_dpp(0, __float_as_int(x), 0x114, 0xf, 0xf, true));
    x += __int_as_float(__builtin_amdgcn_update_dpp(0, __float_as_int(x), 0x118, 0xf, 0xf, true));
    x += __int_as_float(__builtin_amdgcn_update_dpp(0, __float_as_int(x), 0x142, 0xa, 0xf, true));
    x += __int_as_float(__builtin_amdgcn_update_dpp(0, __float_as_int(x), 0x143, 0xc, 0xf, true));
    return x;
}
// sum within each 16-lane row; result valid on lanes 15/31/47/63.
__device__ __forceinline__ float row_sum_dpp(float x) {
    x += __int_as_float(__builtin_amdgcn_update_dpp(0, __float_as_int(x), 0x111, 0xf, 0xf, true));
    x += __int_as_float(__builtin_amdgcn_update_dpp(0, __float_as_int(x), 0x112, 0xf, 0xf, true));
    x += __int_as_float(__builtin_amdgcn_update_dpp(0, __float_as_int(x), 0x114, 0xf, 0xf, true));
    x += __int_as_float(__builtin_amdgcn_update_dpp(0, __float_as_int(x), 0x118, 0xf, 0xf, true));
    return x;
}

// ---------------------------------------------------------------------------
// Kernel 1 (fused prep): blocks 0..511 -> std feature s[t]; block 512 -> sigmas.
// ---------------------------------------------------------------------------
__global__ __launch_bounds__(512) void prep_kernel(
    const float* __restrict__ x,
    const float* __restrict__ w_ih, const float* __restrict__ u_ih,
    const float* __restrict__ w_hh, const float* __restrict__ u_hh,
    const float* __restrict__ fc_w, const float* __restrict__ u_fc,
    float* __restrict__ ws)
{
    const int tid = threadIdx.x;
    __shared__ float rs[16][32];
    __shared__ float rq[16][32];
    __shared__ float red[512];
    __shared__ float vv[128];

    if (blockIdx.x < TT) {
        const int t = blockIdx.x;
        const int c = tid & 31;
        const int sl = tid >> 5;
        float sum = 0.f, sq = 0.f;
        for (int k = 0; k < 32; ++k) {
            const int b = sl * 32 + k;
            float v = x[((size_t)b * TT + t) * CC + c];
            sum += v;
            sq  = fmaf(v, v, sq);
        }
        rs[sl][c] = sum; rq[sl][c] = sq;
        __syncthreads();
        if (tid < 32) {
            float S = 0.f, Q = 0.f;
            for (int i = 0; i < 16; ++i) { S += rs[i][tid]; Q += rq[i][tid]; }
            float mean = S / 512.0f;
            float var  = (Q - 512.0f * mean * mean) / 511.0f;
            rs[0][tid] = sqrtf(fmaxf(var, 0.f));
        }
        __syncthreads();
        if (tid == 0) {
            float m = 0.f;
            for (int i = 0; i < 32; ++i) m += rs[0][i];
            ws[t] = m / 32.0f;
        }
        return;
    }

    const int wv_ = tid >> 6;
    const int l   = tid & 63;

    {   // sigma_hh
        const int c = tid & 127, q = tid >> 7;
        float part = 0.f;
        for (int g = q * 128; g < q * 128 + 128; ++g)
            part = fmaf(w_hh[g * HH + c], u_hh[g], part);
        red[tid] = part;
        __syncthreads();
        if (tid < 128) vv[tid] = red[tid] + red[tid + 128] + red[tid + 256] + red[tid + 384];
        __syncthreads();
        red[tid] = (tid < 128) ? vv[tid] * vv[tid] : 0.f;
        __syncthreads();
        for (int s = 64; s >= 1; s >>= 1) { if (tid < s) red[tid] += red[tid + s]; __syncthreads(); }
        const float nv = sqrtf(red[0]);
        __syncthreads();
        if (tid < 128) vv[tid] = vv[tid] / (nv + EPSF);
        __syncthreads();
        float sq = 0.f;
        for (int gi = 0; gi < 64; ++gi) {
            const int g = wv_ * 64 + gi;
            float2 wl = *reinterpret_cast<const float2*>(&w_hh[(size_t)g * HH + 2 * l]);
            float2 vl = *reinterpret_cast<const float2*>(&vv[2 * l]);
            float p  = fmaf(wl.x, vl.x, wl.y * vl.y);
            float tot = wave_sum_dpp(p);
            sq = fmaf(tot, tot, sq);
        }
        if (l == 63) red[wv_] = sq;
        __syncthreads();
        if (tid == 0) {
            float ns2 = 0.f;
            for (int i = 0; i < 8; ++i) ns2 += red[i];
            ws[513] = ns2 / (sqrtf(ns2) + EPSF);
        }
        __syncthreads();
    }
    {   // sigma_ih
        float part = 0.f;
        if (tid < CIN) {
            for (int g = 0; g < 512; ++g) part = fmaf(w_ih[g * CIN + tid], u_ih[g], part);
            red[tid] = part;
        }
        __syncthreads();
        if (tid == 0) {
            float n2 = 0.f;
            for (int i = 0; i < CIN; ++i) n2 += red[i] * red[i];
            red[400] = sqrtf(n2);
        }
        __syncthreads();
        const float nv = red[400];
        if (tid < CIN) vv[tid] = red[tid] / (nv + EPSF);
        __syncthreads();
        float vl = (l < CIN) ? vv[l] : 0.f;
        float sq = 0.f;
        for (int gi = 0; gi < 64; ++gi) {
            const int g = wv_ * 64 + gi;
            float p = (l < CIN) ? w_ih[(size_t)g * CIN + l] * vl : 0.f;
            float tot = wave_sum_dpp(p);
            sq = fmaf(tot, tot, sq);
        }
        if (l == 63) red[wv_] = sq;
        __syncthreads();
        if (tid == 0) {
            float ns2 = 0.f;
            for (int i = 0; i < 8; ++i) ns2 += red[i];
            ws[512] = ns2 / (sqrtf(ns2) + EPSF);
        }
        __syncthreads();
    }
    {   // sigma_fc
        red[tid] = (tid < 128) ? fc_w[tid] * fc_w[tid] : 0.f;
        __syncthreads();
        for (int s = 64; s >= 1; s >>= 1) { if (tid < s) red[tid] += red[tid + s]; __syncthreads(); }
        if (tid == 0) {
            float nw2 = red[0];
            float u0  = u_fc[0];
            float nv  = fabsf(u0) * sqrtf(nw2);
            float wv  = u0 * nw2 / (nv + EPSF);
            ws[514]   = wv * wv / (fabsf(wv) + EPSF);
        }
    }
}

// ---------------------------------------------------------------------------
// Kernel 2: fp16 MFMA LSTM. 512 blocks x 1 batch row, 512 threads (8 waves),
// waves_per_eu(4,4) -> 2 blocks/CU so two barrier-domains interleave and hide
// each other's serial chain (R11 showed no pipe >46% with 1 block/CU).
// Register fit: x-path restructured -- per 16-step chunk, gates_x[16][128][4]
// is precomputed with 4 MFMAs (x-chunk as A, steps-as-rows; Wih re-read from
// hot L2) into LDS with bias+w32*s_t folded in. Step loop: 16 MFMA (h only),
// 4 hs b128 reads + 1 gxs b128 read. Weight regs 64 (h-part only).
// ---------------------------------------------------------------------------
__global__ __attribute__((amdgpu_flat_work_group_size(512, 512), amdgpu_waves_per_eu(4, 4)))
void lstm_mfma(
    const float* __restrict__ x,
    const float* __restrict__ w_ih, const float* __restrict__ w_hh,
    const float* __restrict__ b_ih, const float* __restrict__ b_hh,
    const float* __restrict__ attn_w, const float* __restrict__ attn_b,
    const float* __restrict__ fc_w, const float* __restrict__ fc_b,
    const float* __restrict__ ws,
    float* __restrict__ out)
{
    const int tid = threadIdx.x;
    const int w   = tid >> 6;          // wave 0..7
    const int l   = tid & 63;          // lane
    const int m   = l & 15;            // A-row / B-col index
    const int q   = l >> 4;            // quad 0..3
    const int b0  = blockIdx.x;        // ONE batch row per block
    const int jcol = 16 * w + m;       // this lane's h column

    const float rih = 1.f / ws[512];
    const float rhh = 1.f / ws[513];
    const float rfc = 1.f / ws[514];
    const float attb = attn_b[0];

    __shared__ __align__(16) _Float16 hs[2][160];        // h planes (1 row)
    __shared__ __align__(16) _Float16 xs[2][CH][48];     // x chunks (1 row)
    __shared__ __align__(16) float ss[2][CH];
    __shared__ __align__(16) float gxs[16][132][4];      // gates_x per chunk
    __shared__ float bcast2[2];
    __shared__ float SfS;
    __shared__ float part[8];

    // ---- stationary fp16 h-weights: Bf[p][kt] (64 VGPRs) ----
    half8 Bf[4][4];
    float biasg[4], w32g[4];
#pragma unroll
    for (int p = 0; p < 4; ++p) {
        const int g = 16 * w + 128 * p + m;
#pragma unroll
        for (int kt = 0; kt < 4; ++kt) {
            const float* src = w_hh + (size_t)g * HH + kt * 32 + q * 8;
#pragma unroll
            for (int i = 0; i < 8; ++i) Bf[p][kt][i] = (_Float16)(src[i] * rhh);
        }
        w32g[p]  = w_ih[(size_t)g * CIN + 32] * rih;
        biasg[p] = b_ih[g] + b_hh[g];
    }
    f32x4 zero4 = (f32x4){0.f, 0.f, 0.f, 0.f};
#pragma unroll
    for (int p = 0; p < 4; ++p) {
#pragma unroll
        for (int kt = 0; kt < 4; ++kt) asm volatile("" : "+v"(Bf[p][kt]));
    }
    asm volatile("" : "+v"(zero4));
    const float fcwj = fc_w[jcol] * rfc;

    // logit-phase constants (wave 0 handles the row, lane = 2 cols)
    const float aw0 = attn_w[2 * l];
    const float aw1 = attn_w[2 * l + 1];

    // zero h_{-1} planes (both buffers)
    for (int i = tid; i < 2 * 160; i += 512) (&hs[0][0])[i] = (_Float16)0.f;
    // stage chunk 0 + ss[0]  (x[b0][0..15][:] is 2 KB contiguous)
    if (tid < 128) {
        const int c4 = tid & 7, k = tid >> 3;
        float4 xv = *reinterpret_cast<const float4*>(x + ((size_t)b0 * TT + k) * CC + c4 * 4);
        half4v hv = {(_Float16)xv.x, (_Float16)xv.y, (_Float16)xv.z, (_Float16)xv.w};
        *(half4v*)&xs[0][k][c4 * 4] = hv;
    }
    if (tid < CH) ss[0][tid] = ws[tid];

    float c_st = 0.f, P = 0.f, hprev = 0.f, hpp = 0.f;
    float Sreg = 0.f;                      // lane 63 of wave 0
    __syncthreads();

    for (int tc = 0; tc < NCH; ++tc) {
        const int cb = tc & 1;

        // ---- gates_x for this chunk: 4 MFMAs, steps-as-rows ----
        {
            half8 Bx[4];
#pragma unroll
            for (int p = 0; p < 4; ++p) {
                const float* src = w_ih + (size_t)(16 * w + 128 * p + m) * CIN + q * 8;
#pragma unroll
                for (int i = 0; i < 8; ++i) Bx[p][i] = (_Float16)(src[i] * rih);
            }
            half8 ax = *(const half8*)&xs[cb][m][q * 8];
            f32x4 d0 = MFMA16H(ax, Bx[0], zero4);
            f32x4 d1 = MFMA16H(ax, Bx[1], zero4);
            f32x4 d2 = MFMA16H(ax, Bx[2], zero4);
            f32x4 d3 = MFMA16H(ax, Bx[3], zero4);
            f32x4 s4 = *(const f32x4*)&ss[cb][4 * q];
#pragma unroll
            for (int i = 0; i < 4; ++i) {
                f32x4 v = (f32x4){ d0[i] + fmaf(w32g[0], s4[i], biasg[0]),
                                   d1[i] + fmaf(w32g[1], s4[i], biasg[1]),
                                   d2[i] + fmaf(w32g[2], s4[i], biasg[2]),
                                   d3[i] + fmaf(w32g[3], s4[i], biasg[3]) };
                *(f32x4*)&gxs[4 * q + i][jcol][0] = v;
            }
        }
        __syncthreads();   // gxs visible

        // ---- stage next chunk (visible by next chunk entry via step barriers) ----
        if (tc + 1 < NCH) {
            const int nb  = (tc + 1) & 1;
            const int t0n = (tc + 1) * CH;
            if (tid < 128) {
                const int c4 = tid & 7, k = tid >> 3;
                float4 xv = *reinterpret_cast<const float4*>(
                    x + ((size_t)b0 * TT + (t0n + k)) * CC + c4 * 4);
                half4v hv = {(_Float16)xv.x, (_Float16)xv.y, (_Float16)xv.z, (_Float16)xv.w};
                *(half4v*)&xs[nb][k][c4 * 4] = hv;
            }
            if (tid < CH) ss[nb][tid] = ws[t0n + tid];
        }

        for (int k = 0; k < CH; ++k) {
            const int t  = tc * CH + k;
            const int hb = (t + 1) & 1;    // buffer holding h_{t-1}

            // ---- A-frags (broadcast reads, 1 row) + gates_x ----
            half8 ah0 = *(const half8*)&hs[hb][0 * 32 + q * 8];
            half8 ah1 = *(const half8*)&hs[hb][1 * 32 + q * 8];
            half8 ah2 = *(const half8*)&hs[hb][2 * 32 + q * 8];
            half8 ah3 = *(const half8*)&hs[hb][3 * 32 + q * 8];
            f32x4 gx4 = *(const f32x4*)&gxs[k][jcol][0];

            // logit source read issued early (h_{t-1})
            float dotp = 0.f;
            if (t > 0 && w == 0) {
                half2v hh = *(const half2v*)&hs[hb][2 * l];
                dotp = fmaf(aw0, (float)hh[0], aw1 * (float)hh[1]);
            }

            // ---- P update for h_{t-2} (beta written at step t-1) ----
            if (t >= 2) P = fmaf(bcast2[(t - 1) & 1], hpp, P);

            // ---- gates: 16 MFMA from zero C, 4 interleaved chains ----
            f32x4 acc0 = MFMA16H(ah0, Bf[0][0], zero4);
            f32x4 acc1 = MFMA16H(ah0, Bf[1][0], zero4);
            f32x4 acc2 = MFMA16H(ah0, Bf[2][0], zero4);
            f32x4 acc3 = MFMA16H(ah0, Bf[3][0], zero4);
            acc0 = MFMA16H(ah1, Bf[0][1], acc0);
            acc1 = MFMA16H(ah1, Bf[1][1], acc1);
            acc2 = MFMA16H(ah1, Bf[2][1], acc2);
            acc3 = MFMA16H(ah1, Bf[3][1], acc3);
            acc0 = MFMA16H(ah2, Bf[0][2], acc0);
            acc1 = MFMA16H(ah2, Bf[1][2], acc1);
            acc2 = MFMA16H(ah2, Bf[2][2], acc2);
            acc3 = MFMA16H(ah2, Bf[3][2], acc3);
            acc0 = MFMA16H(ah3, Bf[0][3], acc0);
            acc1 = MFMA16H(ah3, Bf[1][3], acc1);
            acc2 = MFMA16H(ah3, Bf[2][3], acc2);
            acc3 = MFMA16H(ah3, Bf[3][3], acc3);

            // ---- logit reduction (DPP) overlaps MFMA latency ----
            if (t > 0 && w == 0) {
                float tot = wave_sum_dpp(dotp);
                if (l == 63) {
                    float beta = __expf(tot + attb);
                    Sreg += beta;
                    bcast2[t & 1] = beta;
                }
            }

            // ---- activations: full wave (rows duplicated, reg 0) ----
            {
                float g0 = acc0[0] + gx4[0];
                float g1 = acc1[0] + gx4[1];
                float g2 = acc2[0] + gx4[2];
                float g3 = acc3[0] + gx4[3];
                float ig = fsig(g0);
                float fg = fsig(g1);
                float gg = ftanh(g2);
                float og = fsig(g3);
                c_st = fmaf(fg, c_st, ig * gg);
                float hv = og * ftanh(c_st);
                hpp   = hprev;
                hprev = hv;
                if (l < 16) hs[t & 1][jcol] = (_Float16)hv;
            }

            __syncthreads();   // single barrier per step
        }
    }

    // ---- epilogue ----
    P = fmaf(bcast2[1], hpp, P);              // beta_510 * h_510
    if (w == 0) {                              // beta_511 from hs[1]
        half2v hh = *(const half2v*)&hs[1][2 * l];
        float dotp = fmaf(aw0, (float)hh[0], aw1 * (float)hh[1]);
        float tot = wave_sum_dpp(dotp);
        if (l == 63) {
            float beta = __expf(tot + attb);
            Sreg += beta;
            bcast2[0] = beta;
            SfS = Sreg;
        }
    }
    __syncthreads();
    {
        float Pv = fmaf(bcast2[0], hprev, P);
        float v  = Pv * __builtin_amdgcn_rcpf(SfS) * fcwj;
        float rs = row_sum_dpp(v);
        if (l == 15) part[w] = rs;            // q=0 row: cols 16w..16w+15
    }
    __syncthreads();
    if (tid == 0) {
        float a = 0.f;
#pragma unroll
        for (int i = 0; i < 8; ++i) a += part[i];
        out[b0] = a + fc_b[0];
    }
}

// ---------------------------------------------------------------------------
extern "C" void kernel_launch(void* const* d_in, const int* in_sizes, int n_in,
                              void* d_out, int out_size, void* d_ws, size_t ws_size,
                              hipStream_t stream) {
    const float* x      = (const float*)d_in[0];
    const float* w_ih   = (const float*)d_in[1];
    const float* u_ih   = (const float*)d_in[2];
    const float* w_hh   = (const float*)d_in[3];
    const float* u_hh   = (const float*)d_in[4];
    const float* b_ih   = (const float*)d_in[5];
    const float* b_hh   = (const float*)d_in[6];
    const float* attn_w = (const float*)d_in[7];
    const float* attn_b = (const float*)d_in[8];
    const float* fc_w   = (const float*)d_in[9];
    const float* u_fc   = (const float*)d_in[10];
    const float* fc_b   = (const float*)d_in[11];
    float* ws  = (float*)d_ws;
    float* out = (float*)d_out;

    prep_kernel<<<TT + 1, 512, 0, stream>>>(x, w_ih, u_ih, w_hh, u_hh, fc_w, u_fc, ws);
    lstm_mfma<<<BB, 512, 0, stream>>>(x, w_ih, w_hh, b_ih, b_hh,
                                      attn_w, attn_b, fc_w, fc_b, ws, out);
}

// Round 14
// 502.210 us; speedup vs baseline: 1.2559x; 1.2559x over previous
//
#include <hip/hip_runtime.h>
#include <math.h>

#define TT 512
#define BB 512
#define CC 32
#define CIN 33
#define HH 128
#define EPSF 1e-12f
#define CH 16              // timesteps per x-chunk staged in LDS
#define NCH (TT / CH)
#define RB 2               // batch rows per block
#define HSP 160            // hs row stride (halves): 320 B == 16 banks -> rows disjoint
#define XSP 96             // xs row stride (halves): 192 B == 16 banks

typedef _Float16 half8 __attribute__((ext_vector_type(8)));
typedef _Float16 half4v __attribute__((ext_vector_type(4)));
typedef _Float16 half2v __attribute__((ext_vector_type(2)));
typedef float f32x4 __attribute__((ext_vector_type(4)));

#define MFMA16H(a, b, c) __builtin_amdgcn_mfma_f32_16x16x32_f16(a, b, c, 0, 0, 0)

__device__ __forceinline__ float fsig(float x) {
    return __builtin_amdgcn_rcpf(1.f + __expf(-x));
}
__device__ __forceinline__ float ftanh(float x) {
    return 1.f - 2.f * __builtin_amdgcn_rcpf(1.f + __expf(2.f * x));
}
// full-wave (64) sum via DPP; result valid on lane 63 ONLY.
__device__ __forceinline__ float wave_sum_dpp(float x) {
    x += __int_as_float(__builtin_amdgcn_update_dpp(0, __float_as_int(x), 0x111, 0xf, 0xf, true));
    x += __int_as_float(__builtin_amdgcn_update_dpp(0, __float_as_int(x), 0x112, 0xf, 0xf, true));
    x += __int_as_float(__builtin_amdgcn_update_dpp(0, __float_as_int(x), 0x114, 0xf, 0xf, true));
    x += __int_as_float(__builtin_amdgcn_update_dpp(0, __float_as_int(x), 0x118, 0xf, 0xf, true));
    x += __int_as_float(__builtin_amdgcn_update_dpp(0, __float_as_int(x), 0x142, 0xa, 0xf, true));
    x += __int_as_float(__builtin_amdgcn_update_dpp(0, __float_as_int(x), 0x143, 0xc, 0xf, true));
    return x;
}
// sum within each 16-lane row; result valid on lanes 15/31/47/63.
__device__ __forceinline__ float row_sum_dpp(float x) {
    x += __int_as_float(__builtin_amdgcn_update_dpp(0, __float_as_int(x), 0x111, 0xf, 0xf, true));
    x += __int_as_float(__builtin_amdgcn_update_dpp(0, __float_as_int(x), 0x112, 0xf, 0xf, true));
    x += __int_as_float(__builtin_amdgcn_update_dpp(0, __float_as_int(x), 0x114, 0xf, 0xf, true));
    x += __int_as_float(__builtin_amdgcn_update_dpp(0, __float_as_int(x), 0x118, 0xf, 0xf, true));
    return x;
}

// ---------------------------------------------------------------------------
// Kernel 1 (fused prep): blocks 0..255 -> std feature for t=2b,2b+1 (float4
// loads, 8/thread); block 256 -> sigmas (u-projections parallelized).
// ws[0..511]=s[t], ws[512]=sig_ih, ws[513]=sig_hh, ws[514]=sig_fc
// ---------------------------------------------------------------------------
__global__ __launch_bounds__(512) void prep_kernel(
    const float* __restrict__ x,
    const float* __restrict__ w_ih, const float* __restrict__ u_ih,
    const float* __restrict__ w_hh, const float* __restrict__ u_hh,
    const float* __restrict__ fc_w, const float* __restrict__ u_fc,
    float* __restrict__ ws)
{
    const int tid = threadIdx.x;

    if (blockIdx.x < TT / 2) {
        // ---- std over batch for two timesteps ----
        __shared__ float4 sS[64][8];
        __shared__ float4 sQ[64][8];
        const int c4 = tid & 7;       // c = c4*4 .. c4*4+3
        const int bs = tid >> 3;      // 64 groups of 8 batch rows
#pragma unroll
        for (int tt = 0; tt < 2; ++tt) {
            const int t = 2 * blockIdx.x + tt;
            float4 S = make_float4(0.f, 0.f, 0.f, 0.f);
            float4 Q = make_float4(0.f, 0.f, 0.f, 0.f);
#pragma unroll
            for (int i = 0; i < 8; ++i) {
                const int b = bs * 8 + i;
                float4 v = *reinterpret_cast<const float4*>(
                    x + ((size_t)b * TT + t) * CC + c4 * 4);
                S.x += v.x; S.y += v.y; S.z += v.z; S.w += v.w;
                Q.x = fmaf(v.x, v.x, Q.x); Q.y = fmaf(v.y, v.y, Q.y);
                Q.z = fmaf(v.z, v.z, Q.z); Q.w = fmaf(v.w, v.w, Q.w);
            }
            sS[bs][c4] = S; sQ[bs][c4] = Q;
            __syncthreads();
            for (int s = 32; s >= 1; s >>= 1) {
                if (bs < s) {
                    float4 a = sS[bs][c4], b4 = sS[bs + s][c4];
                    float4 e = sQ[bs][c4], f4 = sQ[bs + s][c4];
                    sS[bs][c4] = make_float4(a.x + b4.x, a.y + b4.y, a.z + b4.z, a.w + b4.w);
                    sQ[bs][c4] = make_float4(e.x + f4.x, e.y + f4.y, e.z + f4.z, e.w + f4.w);
                }
                __syncthreads();
            }
            if (tid < 8) {
                float4 S4 = sS[0][tid], Q4 = sQ[0][tid];
                float st = 0.f;
#pragma unroll
                for (int i = 0; i < 4; ++i) {
                    float s1 = (i == 0) ? S4.x : (i == 1) ? S4.y : (i == 2) ? S4.z : S4.w;
                    float q1 = (i == 0) ? Q4.x : (i == 1) ? Q4.y : (i == 2) ? Q4.z : Q4.w;
                    float mean = s1 / 512.0f;
                    float var  = (q1 - 512.0f * mean * mean) / 511.0f;
                    st += sqrtf(fmaxf(var, 0.f));
                }
                sS[1][tid].x = st;     // stash partial (sum of 4 stds)
            }
            __syncthreads();
            if (tid == 0) {
                float m = 0.f;
                for (int i = 0; i < 8; ++i) m += sS[1][i].x;
                ws[t] = m / 32.0f;
            }
            __syncthreads();
        }
        return;
    }

    // ---- sigmas (single block) ----
    __shared__ float red[512];
    __shared__ float vv[128];
    const int wv_ = tid >> 6;
    const int l   = tid & 63;

    {   // sigma_hh
        const int c = tid & 127, q = tid >> 7;
        float part = 0.f;
        for (int g = q * 128; g < q * 128 + 128; ++g)
            part = fmaf(w_hh[g * HH + c], u_hh[g], part);
        red[tid] = part;
        __syncthreads();
        if (tid < 128) vv[tid] = red[tid] + red[tid + 128] + red[tid + 256] + red[tid + 384];
        __syncthreads();
        red[tid] = (tid < 128) ? vv[tid] * vv[tid] : 0.f;
        __syncthreads();
        for (int s = 64; s >= 1; s >>= 1) { if (tid < s) red[tid] += red[tid + s]; __syncthreads(); }
        const float nv = sqrtf(red[0]);
        __syncthreads();
        if (tid < 128) vv[tid] = vv[tid] / (nv + EPSF);
        __syncthreads();
        float sq = 0.f;
        for (int gi = 0; gi < 64; ++gi) {
            const int g = wv_ * 64 + gi;
            float2 wl = *reinterpret_cast<const float2*>(&w_hh[(size_t)g * HH + 2 * l]);
            float2 vl = *reinterpret_cast<const float2*>(&vv[2 * l]);
            float p  = fmaf(wl.x, vl.x, wl.y * vl.y);
            float tot = wave_sum_dpp(p);
            sq = fmaf(tot, tot, sq);
        }
        if (l == 63) red[wv_] = sq;
        __syncthreads();
        if (tid == 0) {
            float ns2 = 0.f;
            for (int i = 0; i < 8; ++i) ns2 += red[i];
            ws[513] = ns2 / (sqrtf(ns2) + EPSF);
        }
        __syncthreads();
    }
    {   // sigma_ih : u-projection split across 8 waves (was 512-iter serial)
        float part = 0.f;
        if (l < CIN) {
            for (int gi = 0; gi < 64; ++gi) {
                const int g = wv_ * 64 + gi;
                part = fmaf(w_ih[(size_t)g * CIN + l], u_ih[g], part);
            }
            red[wv_ * 64 + l] = part;
        }
        __syncthreads();
        if (tid < CIN) {
            float v = 0.f;
#pragma unroll
            for (int i = 0; i < 8; ++i) v += red[i * 64 + tid];
            vv[tid] = v;
        }
        __syncthreads();
        if (tid == 0) {
            float n2 = 0.f;
            for (int i = 0; i < CIN; ++i) n2 += vv[i] * vv[i];
            red[400] = sqrtf(n2);
        }
        __syncthreads();
        const float nv = red[400];
        if (tid < CIN) vv[tid] = vv[tid] / (nv + EPSF);
        __syncthreads();
        float vl = (l < CIN) ? vv[l] : 0.f;
        float sq = 0.f;
        for (int gi = 0; gi < 64; ++gi) {
            const int g = wv_ * 64 + gi;
            float p = (l < CIN) ? w_ih[(size_t)g * CIN + l] * vl : 0.f;
            float tot = wave_sum_dpp(p);
            sq = fmaf(tot, tot, sq);
        }
        if (l == 63) red[wv_] = sq;
        __syncthreads();
        if (tid == 0) {
            float ns2 = 0.f;
            for (int i = 0; i < 8; ++i) ns2 += red[i];
            ws[512] = ns2 / (sqrtf(ns2) + EPSF);
        }
        __syncthreads();
    }
    {   // sigma_fc
        red[tid] = (tid < 128) ? fc_w[tid] * fc_w[tid] : 0.f;
        __syncthreads();
        for (int s = 64; s >= 1; s >>= 1) { if (tid < s) red[tid] += red[tid + s]; __syncthreads(); }
        if (tid == 0) {
            float nw2 = red[0];
            float u0  = u_fc[0];
            float nv  = fabsf(u0) * sqrtf(nw2);
            float wv  = u0 * nw2 / (nv + EPSF);
            ws[514]   = wv * wv / (fabsf(wv) + EPSF);
        }
    }
}

// ---------------------------------------------------------------------------
// Kernel 2: fp16 MFMA LSTM — R11 structure (known-good 394 us / 0 conflicts).
// 256 blocks x 2 batch rows, 512 threads (8 waves, 2/SIMD). Duplicate-row
// A-frags (all lanes), bank-exact padding HSP=160/XSP=96, zero-C MFMA start,
// DPP logit reduction, single barrier per step.
// R13 lesson: 2 blocks/CU requires RB=1 (2x MFMA work) or 128-reg budget
// (spills 22 MB) -- both net losses. This structure is the floor.
// ---------------------------------------------------------------------------
__global__ __attribute__((amdgpu_flat_work_group_size(512, 512), amdgpu_waves_per_eu(2, 2)))
void lstm_mfma(
    const float* __restrict__ x,
    const float* __restrict__ w_ih, const float* __restrict__ w_hh,
    const float* __restrict__ b_ih, const float* __restrict__ b_hh,
    const float* __restrict__ attn_w, const float* __restrict__ attn_b,
    const float* __restrict__ fc_w, const float* __restrict__ fc_b,
    const float* __restrict__ ws,
    float* __restrict__ out)
{
    const int tid = threadIdx.x;
    const int w   = tid >> 6;          // wave 0..7
    const int l   = tid & 63;          // lane
    const int m   = l & 15;            // A-row / B-col index
    const int q   = l >> 4;            // quad 0..3
    const int r   = q & 1;             // this lane's batch row (duplicated rows)
    const int b0  = blockIdx.x * RB;
    const int jcol = 16 * w + m;       // this lane's h column

    const float rih = 1.f / ws[512];
    const float rhh = 1.f / ws[513];
    const float rfc = 1.f / ws[514];
    const float attb = attn_b[0];

    __shared__ __align__(16) _Float16 hs[2][RB][HSP];       // h planes
    __shared__ __align__(16) _Float16 xs[2][CH][RB][XSP];   // x chunks
    __shared__ float ss[2][CH];
    __shared__ __align__(8) float bcast[2][RB];             // beta per row
    __shared__ float Sf[RB];
    __shared__ float part[8][RB];                           // FC partials

    // ---- stationary fp16 weights: Bf[p][kt] ----
    half8 Bf[4][5];
    float biasg[4], w32g[4];
#pragma unroll
    for (int p = 0; p < 4; ++p) {
        const int g = 16 * w + 128 * p + m;
#pragma unroll
        for (int kt = 0; kt < 4; ++kt) {
            const float* src = w_hh + (size_t)g * HH + kt * 32 + q * 8;
#pragma unroll
            for (int i = 0; i < 8; ++i) Bf[p][kt][i] = (_Float16)(src[i] * rhh);
        }
        {
            const float* src = w_ih + (size_t)g * CIN + q * 8;
#pragma unroll
            for (int i = 0; i < 8; ++i) Bf[p][4][i] = (_Float16)(src[i] * rih);
        }
        w32g[p]  = w_ih[(size_t)g * CIN + 32] * rih;
        biasg[p] = b_ih[g] + b_hh[g];
    }
    f32x4 zero4 = (f32x4){0.f, 0.f, 0.f, 0.f};
#pragma unroll
    for (int p = 0; p < 4; ++p) {
#pragma unroll
        for (int kt = 0; kt < 5; ++kt) asm volatile("" : "+v"(Bf[p][kt]));
        asm volatile("" : "+v"(biasg[p]), "+v"(w32g[p]));
    }
    asm volatile("" : "+v"(zero4));
    const float fcwj = fc_w[jcol] * rfc;

    // logit-phase constants (waves 0..1 handle batch rows 0..1, lane = 2 cols)
    const float aw0 = attn_w[2 * l];
    const float aw1 = attn_w[2 * l + 1];

    // zero h_{-1} planes (both buffers)
    for (int i = tid; i < 2 * RB * HSP; i += 512) (&hs[0][0][0])[i] = (_Float16)0.f;
    // stage chunk 0 + ss[0]
    if (tid < 256) {
        const int c4 = tid & 7, rr = (tid >> 3) & 1, k = tid >> 4;
        float4 xv = *reinterpret_cast<const float4*>(x + ((size_t)(b0 + rr) * TT + k) * CC + c4 * 4);
        half4v hv = {(_Float16)xv.x, (_Float16)xv.y, (_Float16)xv.z, (_Float16)xv.w};
        *(half4v*)&xs[0][k][rr][c4 * 4] = hv;
    }
    if (tid < CH) ss[0][tid] = ws[tid];

    float c_st = 0.f, P = 0.f, hprev = 0.f, hpp = 0.f;  // per-lane, row r
    float Sreg = 0.f;                                    // lane 63 of waves 0,1
    __syncthreads();

    for (int tc = 0; tc < NCH; ++tc) {
        const int cb = tc & 1;

        // stage next chunk
        if (tc + 1 < NCH) {
            const int nb  = (tc + 1) & 1;
            const int t0n = (tc + 1) * CH;
            if (tid < 256) {
                const int c4 = tid & 7, rr = (tid >> 3) & 1, k = tid >> 4;
                float4 xv = *reinterpret_cast<const float4*>(
                    x + ((size_t)(b0 + rr) * TT + (t0n + k)) * CC + c4 * 4);
                half4v hv = {(_Float16)xv.x, (_Float16)xv.y, (_Float16)xv.z, (_Float16)xv.w};
                *(half4v*)&xs[nb][k][rr][c4 * 4] = hv;
            }
            if (tid < CH) ss[nb][tid] = ws[t0n + tid];
        }

        for (int k = 0; k < CH; ++k) {
            const int t  = tc * CH + k;
            const int hb = (t + 1) & 1;    // buffer holding h_{t-1}

            // ---- A-frags: all lanes read duplicated rows (m&1) ----
            half8 ah0 = *(const half8*)&hs[hb][m & 1][0 * 32 + q * 8];
            half8 ah1 = *(const half8*)&hs[hb][m & 1][1 * 32 + q * 8];
            half8 ah2 = *(const half8*)&hs[hb][m & 1][2 * 32 + q * 8];
            half8 ah3 = *(const half8*)&hs[hb][m & 1][3 * 32 + q * 8];
            half8 ah4 = *(const half8*)&xs[cb][k][m & 1][q * 8];
            const float s_t = ss[cb][k];

            // logit source read issued early (h_{t-1}, buffer hb)
            float dotp = 0.f;
            if (t > 0 && w < RB) {
                half2v hh = *(const half2v*)&hs[hb][w][2 * l];
                dotp = fmaf(aw0, (float)hh[0], aw1 * (float)hh[1]);
            }

            // ---- P update for h_{t-2} (beta written at step t-1) ----
            if (t >= 2) P = fmaf(bcast[(t - 1) & 1][r], hpp, P);

            // ---- gates: 20 MFMA from zero C, 4 interleaved chains ----
            f32x4 acc0 = MFMA16H(ah0, Bf[0][0], zero4);
            f32x4 acc1 = MFMA16H(ah0, Bf[1][0], zero4);
            f32x4 acc2 = MFMA16H(ah0, Bf[2][0], zero4);
            f32x4 acc3 = MFMA16H(ah0, Bf[3][0], zero4);
            acc0 = MFMA16H(ah1, Bf[0][1], acc0);
            acc1 = MFMA16H(ah1, Bf[1][1], acc1);
            acc2 = MFMA16H(ah1, Bf[2][1], acc2);
            acc3 = MFMA16H(ah1, Bf[3][1], acc3);
            acc0 = MFMA16H(ah2, Bf[0][2], acc0);
            acc1 = MFMA16H(ah2, Bf[1][2], acc1);
            acc2 = MFMA16H(ah2, Bf[2][2], acc2);
            acc3 = MFMA16H(ah2, Bf[3][2], acc3);
            acc0 = MFMA16H(ah3, Bf[0][3], acc0);
            acc1 = MFMA16H(ah3, Bf[1][3], acc1);
            acc2 = MFMA16H(ah3, Bf[2][3], acc2);
            acc3 = MFMA16H(ah3, Bf[3][3], acc3);
            acc0 = MFMA16H(ah4, Bf[0][4], acc0);
            acc1 = MFMA16H(ah4, Bf[1][4], acc1);
            acc2 = MFMA16H(ah4, Bf[2][4], acc2);
            acc3 = MFMA16H(ah4, Bf[3][4], acc3);

            // ---- logit reduction (DPP) overlaps MFMA latency ----
            if (t > 0 && w < RB) {
                float tot = wave_sum_dpp(dotp);
                if (l == 63) {
                    float beta = __expf(tot + attb);
                    Sreg += beta;
                    bcast[t & 1][w] = beta;
                }
            }

            // ---- activations: full wave, reg r = this lane's row ----
            {
                float g0 = acc0[r] + fmaf(w32g[0], s_t, biasg[0]);
                float g1 = acc1[r] + fmaf(w32g[1], s_t, biasg[1]);
                float g2 = acc2[r] + fmaf(w32g[2], s_t, biasg[2]);
                float g3 = acc3[r] + fmaf(w32g[3], s_t, biasg[3]);
                float ig = fsig(g0);
                float fg = fsig(g1);
                float gg = ftanh(g2);
                float og = fsig(g3);
                c_st = fmaf(fg, c_st, ig * gg);
                float hv = og * ftanh(c_st);
                hpp   = hprev;
                hprev = hv;
                if (q < 2) hs[t & 1][r][jcol] = (_Float16)hv;
            }

            __syncthreads();   // single barrier per step
        }
    }

    // ---- epilogue ----
    // pending 1: beta_510 (bcast[1], written at t=511) applied to hpp=h_510
    P = fmaf(bcast[1][r], hpp, P);
    // pending 2: logit for h_511 (buffer 1)
    if (w < RB) {
        half2v hh = *(const half2v*)&hs[1][w][2 * l];
        float dotp = fmaf(aw0, (float)hh[0], aw1 * (float)hh[1]);
        float tot = wave_sum_dpp(dotp);
        if (l == 63) {
            float beta = __expf(tot + attb);
            Sreg += beta;
            bcast[0][w] = beta;
            Sf[w] = Sreg;
        }
    }
    __syncthreads();
    // final P, scale, per-row reduce (16-lane rows independent in DPP)
    {
        float Pv = fmaf(bcast[0][r], hprev, P);
        float v  = Pv * __builtin_amdgcn_rcpf(Sf[r]) * fcwj;
        float rs = row_sum_dpp(v);
        if (l == 15) part[w][0] = rs;       // row 0 sum (q=0)
        if (l == 31) part[w][1] = rs;       // row 1 sum (q=1)
    }
    __syncthreads();
    if (tid < RB) {
        float a = 0.f;
#pragma unroll
        for (int i = 0; i < 8; ++i) a += part[i][tid];
        out[b0 + tid] = a + fc_b[0];
    }
}

// ---------------------------------------------------------------------------
extern "C" void kernel_launch(void* const* d_in, const int* in_sizes, int n_in,
                              void* d_out, int out_size, void* d_ws, size_t ws_size,
                              hipStream_t stream) {
    const float* x      = (const float*)d_in[0];
    const float* w_ih   = (const float*)d_in[1];
    const float* u_ih   = (const float*)d_in[2];
    const float* w_hh   = (const float*)d_in[3];
    const float* u_hh   = (const float*)d_in[4];
    const float* b_ih   = (const float*)d_in[5];
    const float* b_hh   = (const float*)d_in[6];
    const float* attn_w = (const float*)d_in[7];
    const float* attn_b = (const float*)d_in[8];
    const float* fc_w   = (const float*)d_in[9];
    const float* u_fc   = (const float*)d_in[10];
    const float* fc_b   = (const float*)d_in[11];
    float* ws  = (float*)d_ws;
    float* out = (float*)d_out;

    prep_kernel<<<TT / 2 + 1, 512, 0, stream>>>(x, w_ih, u_ih, w_hh, u_hh, fc_w, u_fc, ws);
    lstm_mfma<<<BB / RB, 512, 0, stream>>>(x, w_ih, w_hh, b_ih, b_hh,
                                           attn_w, attn_b, fc_w, fc_b, ws, out);
}